// Round 1
// 609.832 us; speedup vs baseline: 1.0158x; 1.0158x over previous
//
#include <hip/hip_runtime.h>

// Problem constants: B=4, C=64 (in & out for deform), H=W=256.
#define BB 4
#define CC 64
#define HH 256
#define WW 256
#define HWHW 65536

typedef __bf16 bf16x8 __attribute__((ext_vector_type(8)));
typedef float f32x16 __attribute__((ext_vector_type(16)));
typedef unsigned int uint4v __attribute__((ext_vector_type(4)));
typedef unsigned int uint2v __attribute__((ext_vector_type(2)));

__device__ __forceinline__ unsigned short f32_to_bf16(float s) {
    unsigned int xi = __builtin_bit_cast(unsigned int, s);
    unsigned int r = (xi + 0x7fffu + ((xi >> 16) & 1u)) >> 16;  // RNE
    return (unsigned short)r;
}

// ---------------------------------------------------------------------------
// Prep:
//   wA[c][k][o18]  fp32, from offset_w[o][c][ky][kx]  (offset conv weights)
//   WB2: bf16 deform weights in MFMA-ready LDS layout, TAP-MAJOR K order:
//        [chunk(4)][kslot(18)][n(64)][j(8)] where k_local = kslot*8+j,
//        tap = k_local/16, c = chunk*16 + (k_local%16), value = dc_w[n][c][tap]
// ---------------------------------------------------------------------------
__global__ void prep_weights(const float* __restrict__ offset_w,
                             const float* __restrict__ dc_w,
                             float* __restrict__ wA,
                             unsigned short* __restrict__ WB2) {
    int idx = blockIdx.x * 256 + threadIdx.x;
    const int NA = CC * 9 * 18;            // 10368
    const int NB = 4 * 18 * 64 * 8;        // 36864
    if (idx < NA) {
        int c = idx / (9 * 18);
        int k = (idx / 18) % 9;
        int o = idx % 18;
        wA[idx] = offset_w[(o * CC + c) * 9 + k];
    }
    int j = idx - NA;
    if (j >= 0 && j < NB) {
        int chunk = j / 9216;              // 9216 = 18*64*8
        int rem = j - chunk * 9216;
        int kslot = rem >> 9;              // /(64*8)
        int n = (rem >> 3) & 63;
        int jj = rem & 7;
        int k_local = kslot * 8 + jj;      // < 144, tap-major
        int tap = k_local >> 4;
        int c_local = k_local & 15;
        int c = chunk * 16 + c_local;
        WB2[j] = f32_to_bf16(dc_w[(n * CC + c) * 9 + tap]);
    }
}

// ---------------------------------------------------------------------------
// Offset conv (unchanged, fp32-exact): 3x3, pad 1, 64 -> 18 channels.
// ---------------------------------------------------------------------------
__global__ __launch_bounds__(256) void offset_conv(
    const float* __restrict__ blur, const float* __restrict__ wA,
    const float* __restrict__ ob, float* __restrict__ offout) {
    const int x = threadIdx.x;
    const int y = blockIdx.x & (HH - 1);
    const int b = blockIdx.x >> 8;

    int rb[3], cx[3];
    float m[9];
#pragma unroll
    for (int dy = 0; dy < 3; ++dy) {
        int yy = y + dy - 1;
        rb[dy] = min(max(yy, 0), HH - 1) * WW;
        bool vy = (yy >= 0) && (yy < HH);
#pragma unroll
        for (int dx = 0; dx < 3; ++dx) {
            int xx = x + dx - 1;
            bool v = vy && (xx >= 0) && (xx < WW);
            m[dy * 3 + dx] = v ? 1.0f : 0.0f;
        }
    }
#pragma unroll
    for (int dx = 0; dx < 3; ++dx) cx[dx] = min(max(x + dx - 1, 0), WW - 1);

    float acc[18];
#pragma unroll
    for (int o = 0; o < 18; ++o) acc[o] = ob[o];

    const float* img = blur + (size_t)b * CC * HWHW;
    for (int c = 0; c < CC; ++c) {
        const float* pl = img + c * HWHW;
        float s[9];
#pragma unroll
        for (int dy = 0; dy < 3; ++dy)
#pragma unroll
            for (int dx = 0; dx < 3; ++dx)
                s[dy * 3 + dx] = pl[rb[dy] + cx[dx]] * m[dy * 3 + dx];

        const float* wp = wA + c * 9 * 18;
#pragma unroll
        for (int k = 0; k < 9; ++k) {
            float sv = s[k];
#pragma unroll
            for (int o = 0; o < 18; ++o)
                acc[o] = fmaf(sv, wp[k * 18 + o], acc[o]);
        }
    }

    float* op = offout + ((size_t)b * 18) * HWHW + y * WW + x;
#pragma unroll
    for (int o = 0; o < 18; ++o) op[(size_t)o * HWHW] = acc[o];
}

// ---------------------------------------------------------------------------
// Deformable conv as implicit GEMM on MFMA.
// Block = 256 thr = 4 waves, tile = 64 pixels x 64 outs. K = 576, 4 x 144.
// Phase 0: per-(px,tap) bilinear state computed ONCE -> LDS (24 B each).
// Producer: thread (px, cg) per chunk: 9 taps x 4 channels; per tap reloads
//   tiny state from LDS (b128+b64), 16 gather loads, packs 4 bf16 -> one
//   8B LDS write at tap-major k_local = tap*16 + cg*4 + i.
// Consumer: wave w computes 32x32 quadrant via 9x mfma_f32_32x32x16_bf16;
//   B-fragments read straight from L2-resident global (no LDS staging).
// LDS = 18432 (samples) + 9216 (stateW) + 4608 (stateI) = 32256 B
//   -> 5 blocks/CU; __launch_bounds__(256,5) caps VGPRs to match.
// ---------------------------------------------------------------------------
__global__ __launch_bounds__(256, 5) void deform_mfma(
    const float* __restrict__ content, const float* __restrict__ offs,
    const unsigned short* __restrict__ WB2, const float* __restrict__ bias,
    float* __restrict__ out) {
    __shared__ char ldsbuf[32256];
    unsigned int* sampU = (unsigned int*)ldsbuf;             // [18][64][4] uints
    float4* stateW = (float4*)(ldsbuf + 18432);              // [9][64]
    int2* stateI = (int2*)(ldsbuf + 18432 + 9216);           // [9][64]
    float* ldsOut = (float*)ldsbuf;                          // [64][65] (epilogue alias)

    const int t = threadIdx.x;
    const int px = t & 63;
    const int cg = t >> 6;                 // wave id == channel group
    const int blk = blockIdx.x;
    const int xseg = blk & 3;
    const int y = (blk >> 2) & (HH - 1);
    const int b = blk >> 10;

    // ---- phase 0: bilinear state for 64 px x 9 taps, computed once ----
    {
        const float* offbase = offs + (size_t)b * 18 * HWHW + y * WW + xseg * 64;
        for (int i = t; i < 576; i += 256) {
            const int p = i & 63;
            const int tap = i >> 6;
            const int ky = tap / 3, kx = tap - ky * 3;
            const float offy = offbase[(size_t)(2 * tap) * HWHW + p];
            const float offx = offbase[(size_t)(2 * tap + 1) * HWHW + p];
            const float py = (float)(y + ky - 1) + offy;
            const float pxf = (float)(xseg * 64 + p + kx - 1) + offx;
            const float y0f = floorf(py), x0f = floorf(pxf);
            const float wy = py - y0f, wx = pxf - x0f;
            const int y0 = (int)y0f, x0 = (int)x0f;

            float a00 = (1.0f - wy) * (1.0f - wx);
            float a01 = (1.0f - wy) * wx;
            float a10 = wy * (1.0f - wx);
            float a11 = wy * wx;
            const bool vy0 = (y0 >= 0) && (y0 < HH);
            const bool vy1 = (y0 + 1 >= 0) && (y0 + 1 < HH);
            const bool vx0 = (x0 >= 0) && (x0 < WW);
            const bool vx1 = (x0 + 1 >= 0) && (x0 + 1 < WW);
            float4 w;
            w.x = (vy0 && vx0) ? a00 : 0.0f;
            w.y = (vy0 && vx1) ? a01 : 0.0f;
            w.z = (vy1 && vx0) ? a10 : 0.0f;
            w.w = (vy1 && vx1) ? a11 : 0.0f;

            const int y0c = min(max(y0, 0), HH - 1);
            const int y1c = min(max(y0 + 1, 0), HH - 1);
            const int x0c = min(max(x0, 0), WW - 1);
            const int x1c = min(max(x0 + 1, 0), WW - 1);
            const int i00 = y0c * WW + x0c;
            const int dx1 = x1c - x0c;           // 0 or 1
            const int dyW = (y1c - y0c) * WW;    // 0 or WW

            stateW[tap * 64 + p] = w;
            stateI[tap * 64 + p] = make_int2(i00, dyW | (dx1 << 16));
        }
    }
    __syncthreads();

    const float* img = content + (size_t)b * CC * HWHW;

    f32x16 acc = {0, 0, 0, 0, 0, 0, 0, 0, 0, 0, 0, 0, 0, 0, 0, 0};

    const int lane = t & 63;
    const int half = lane >> 5;
    const int l31 = lane & 31;
    const int px_i = ((cg >> 1) * 32) + l31;   // A-frag pixel row
    const int n_i = ((cg & 1) * 32) + l31;     // B-frag out-channel col

    for (int chunk = 0; chunk < 4; ++chunk) {
        // ---- produce: 9 taps x 4 channels, tap-major k ordering ----
        {
            const int cbase = (chunk * 16 + cg * 4) << 16;   // HWHW == 1<<16
#pragma unroll 3
            for (int tap = 0; tap < 9; ++tap) {
                const float4 w = stateW[tap * 64 + px];
                const int2 ii = stateI[tap * 64 + px];
                const int i0 = ii.x;
                const int dyw = ii.y & 0xffff;
                const int dx = ii.y >> 16;

                unsigned int pk0 = 0, pk1 = 0;
#pragma unroll
                for (int i = 0; i < 4; ++i) {
                    const int cb = cbase + (i << 16);
                    const float v00 = img[cb + i0];
                    const float v01 = img[cb + i0 + dx];
                    const float v10 = img[cb + i0 + dyw];
                    const float v11 = img[cb + i0 + dyw + dx];
                    const float s = w.x * v00 + w.y * v01 + w.z * v10 + w.w * v11;
                    const unsigned int u = f32_to_bf16(s);
                    if (i == 0) pk0 = u;
                    else if (i == 1) pk0 |= u << 16;
                    else if (i == 2) pk1 = u;
                    else pk1 |= u << 16;
                }
                // k_local = tap*16 + cg*4 + i -> slot tap*2 + (cg>>1), uints (cg&1)*2..+1
                uint2v v2 = {pk0, pk1};
                *(uint2v*)&sampU[(tap * 2 + (cg >> 1)) * 256 + px * 4 + (cg & 1) * 2] = v2;
            }
        }
        __syncthreads();

        // ---- MFMA: 9 x K16; B-frags direct from global (L2-hot 36KB) ----
        {
            const bf16x8* sampV = (const bf16x8*)sampU;
            const bf16x8* wV = (const bf16x8*)(WB2 + (size_t)chunk * 9216);
#pragma unroll
            for (int ks = 0; ks < 9; ++ks) {
                bf16x8 fa = sampV[(ks * 2 + half) * 64 + px_i];
                bf16x8 fb = wV[(ks * 2 + half) * 64 + n_i];
                acc = __builtin_amdgcn_mfma_f32_32x32x16_bf16(fa, fb, acc, 0, 0, 0);
            }
        }
        __syncthreads();
    }

    // ---- epilogue: transpose via LDS (stride 65, bank-clean), coalesced out ----
    {
        const int n_l = (cg & 1) * 32 + l31;
        const int px_base = (cg >> 1) * 32 + 4 * half;
#pragma unroll
        for (int r = 0; r < 16; ++r) {
            const int row = px_base + (r & 3) + 8 * (r >> 2);
            ldsOut[n_l * 65 + row] = acc[r];
        }
    }
    __syncthreads();
    {
        float* base = out + (size_t)b * CC * HWHW + y * WW + xseg * 64;
        for (int i = t; i < 4096; i += 256) {
            const int n = i >> 6;
            const int p = i & 63;
            base[(size_t)n * HWHW + p] = ldsOut[n * 65 + p] + bias[n];
        }
    }
}

// ---------------------------------------------------------------------------
extern "C" void kernel_launch(void* const* d_in, const int* in_sizes, int n_in,
                              void* d_out, int out_size, void* d_ws, size_t ws_size,
                              hipStream_t stream) {
    const float* content  = (const float*)d_in[0];
    const float* blur     = (const float*)d_in[1];
    const float* offset_w = (const float*)d_in[2];
    const float* offset_b = (const float*)d_in[3];
    const float* dc_w     = (const float*)d_in[4];
    const float* dc_b     = (const float*)d_in[5];

    float* out0    = (float*)d_out;                                // (4,64,256,256)
    float* off_out = out0 + (size_t)BB * CC * HWHW;                // (4,18,256,256)

    float* wA = (float*)d_ws;                               // 10368 floats
    unsigned short* WB2 = (unsigned short*)(wA + CC * 9 * 18);  // 36864 bf16

    const int NPREP = CC * 9 * 18 + 4 * 18 * 64 * 8;        // 47232
    prep_weights<<<(NPREP + 255) / 256, 256, 0, stream>>>(offset_w, dc_w, wA, WB2);
    offset_conv<<<BB * HH, 256, 0, stream>>>(blur, wA, offset_b, off_out);
    deform_mfma<<<BB * HH * 4, 256, 0, stream>>>(content, off_out, WB2, dc_b, out0);
}

// Round 2
// 556.527 us; speedup vs baseline: 1.1131x; 1.0958x over previous
//
#include <hip/hip_runtime.h>

// Problem constants: B=4, C=64 (in & out for deform), H=W=256.
#define BB 4
#define CC 64
#define HH 256
#define WW 256
#define HWHW 65536

typedef __bf16 bf16x8 __attribute__((ext_vector_type(8)));
typedef float f32x16 __attribute__((ext_vector_type(16)));
typedef unsigned int uint2v __attribute__((ext_vector_type(2)));

typedef const unsigned int __attribute__((address_space(1))) gu32_t;
typedef unsigned int __attribute__((address_space(3))) lu32_t;

__device__ __forceinline__ unsigned short f32_to_bf16(float s) {
    unsigned int xi = __builtin_bit_cast(unsigned int, s);
    unsigned int r = (xi + 0x7fffu + ((xi >> 16) & 1u)) >> 16;  // RNE
    return (unsigned short)r;
}

// ---------------------------------------------------------------------------
// Prep:
//   wA[c][k][o18]  fp32, from offset_w[o][c][ky][kx]  (offset conv weights)
//   WB2: bf16 deform weights, TAP-MAJOR K order:
//        [chunk(4)][kslot(18)][n(64)][j(8)], k_local = kslot*8+j,
//        tap = k_local/16, c = chunk*16 + (k_local%16), value = dc_w[n][c][tap]
// ---------------------------------------------------------------------------
__global__ void prep_weights(const float* __restrict__ offset_w,
                             const float* __restrict__ dc_w,
                             float* __restrict__ wA,
                             unsigned short* __restrict__ WB2) {
    int idx = blockIdx.x * 256 + threadIdx.x;
    const int NA = CC * 9 * 18;            // 10368
    const int NB = 4 * 18 * 64 * 8;        // 36864
    if (idx < NA) {
        int c = idx / (9 * 18);
        int k = (idx / 18) % 9;
        int o = idx % 18;
        wA[idx] = offset_w[(o * CC + c) * 9 + k];
    }
    int j = idx - NA;
    if (j >= 0 && j < NB) {
        int chunk = j / 9216;              // 9216 = 18*64*8
        int rem = j - chunk * 9216;
        int kslot = rem >> 9;              // /(64*8)
        int n = (rem >> 3) & 63;
        int jj = rem & 7;
        int k_local = kslot * 8 + jj;      // < 144, tap-major
        int tap = k_local >> 4;
        int c_local = k_local & 15;
        int c = chunk * 16 + c_local;
        WB2[j] = f32_to_bf16(dc_w[(n * CC + c) * 9 + tap]);
    }
}

// ---------------------------------------------------------------------------
// Offset conv (unchanged, fp32-exact): 3x3, pad 1, 64 -> 18 channels.
// ---------------------------------------------------------------------------
__global__ __launch_bounds__(256) void offset_conv(
    const float* __restrict__ blur, const float* __restrict__ wA,
    const float* __restrict__ ob, float* __restrict__ offout) {
    const int x = threadIdx.x;
    const int y = blockIdx.x & (HH - 1);
    const int b = blockIdx.x >> 8;

    int rb[3], cx[3];
    float m[9];
#pragma unroll
    for (int dy = 0; dy < 3; ++dy) {
        int yy = y + dy - 1;
        rb[dy] = min(max(yy, 0), HH - 1) * WW;
        bool vy = (yy >= 0) && (yy < HH);
#pragma unroll
        for (int dx = 0; dx < 3; ++dx) {
            int xx = x + dx - 1;
            bool v = vy && (xx >= 0) && (xx < WW);
            m[dy * 3 + dx] = v ? 1.0f : 0.0f;
        }
    }
#pragma unroll
    for (int dx = 0; dx < 3; ++dx) cx[dx] = min(max(x + dx - 1, 0), WW - 1);

    float acc[18];
#pragma unroll
    for (int o = 0; o < 18; ++o) acc[o] = ob[o];

    const float* img = blur + (size_t)b * CC * HWHW;
    for (int c = 0; c < CC; ++c) {
        const float* pl = img + c * HWHW;
        float s[9];
#pragma unroll
        for (int dy = 0; dy < 3; ++dy)
#pragma unroll
            for (int dx = 0; dx < 3; ++dx)
                s[dy * 3 + dx] = pl[rb[dy] + cx[dx]] * m[dy * 3 + dx];

        const float* wp = wA + c * 9 * 18;
#pragma unroll
        for (int k = 0; k < 9; ++k) {
            float sv = s[k];
#pragma unroll
            for (int o = 0; o < 18; ++o)
                acc[o] = fmaf(sv, wp[k * 18 + o], acc[o]);
        }
    }

    float* op = offout + ((size_t)b * 18) * HWHW + y * WW + x;
#pragma unroll
    for (int o = 0; o < 18; ++o) op[(size_t)o * HWHW] = acc[o];
}

// ---------------------------------------------------------------------------
// Deformable conv as implicit GEMM on MFMA.
// Block = 256 thr = 4 waves, tile = 64 px x 64 outs, K = 576 (4 chunks x 144).
//
// The gather was TA/L1-bound (600M divergent lane-loads; duration invariant
// to occupancy). Fix: per 8-channel half-chunk, stage the content window
// (rows ymin..+9, cols xmin..+75, measured per block from the actual offsets)
// into LDS with coalesced global_load_lds, then do the bilinear gather as
// ds_read_b32 from LDS. Block-uniform fallback to global gather if the
// window doesn't fit (never for this data distribution, correct always).
// LDS: samp 18432 | tile 8x10x76 f32 = 24320 | stateW 9216 | stateI 2304 |
//      bnd 16  => 54288 B -> 3 blocks/CU.
// ---------------------------------------------------------------------------
__global__ __launch_bounds__(256, 3) void deform_mfma(
    const float* __restrict__ content, const float* __restrict__ offs,
    const unsigned short* __restrict__ WB2, const float* __restrict__ bias,
    float* __restrict__ out) {
    __shared__ __align__(16) char ldsbuf[54288];
    unsigned int* sampU = (unsigned int*)ldsbuf;              // [18][64][4] uints
    unsigned int* tileU = (unsigned int*)(ldsbuf + 18432);    // [8][10][76] f32
    float* tileF = (float*)tileU;
    float4* stateW = (float4*)(ldsbuf + 42752);               // [9][64]
    unsigned int* stateI = (unsigned int*)(ldsbuf + 51968);   // [9][64] packed
    int* bnd = (int*)(ldsbuf + 54272);                        // ymin,ymax,xmin,xmax
    float* ldsOut = (float*)ldsbuf;                           // [64][65] (epilogue alias)

    const int t = threadIdx.x;
    const int px = t & 63;
    const int cg = t >> 6;                 // wave id
    const int blk = blockIdx.x;
    const int xseg = blk & 3;
    const int y = (blk >> 2) & (HH - 1);
    const int b = blk >> 10;

    if (t < 4) bnd[t] = (t & 1) ? 0 : 255;   // mins init 255, maxs init 0

    // ---- phase 0: bilinear state for 64 px x 9 taps + block sample bounds ----
    int lymin = 255, lymax = 0, lxmin = 255, lxmax = 0;
    {
        const float* offbase = offs + (size_t)b * 18 * HWHW + y * WW + xseg * 64;
        for (int i = t; i < 576; i += 256) {
            const int p = i & 63;
            const int tap = i >> 6;
            const int ky = tap / 3, kx = tap - ky * 3;
            const float offy = offbase[(size_t)(2 * tap) * HWHW + p];
            const float offx = offbase[(size_t)(2 * tap + 1) * HWHW + p];
            const float py = (float)(y + ky - 1) + offy;
            const float pxf = (float)(xseg * 64 + p + kx - 1) + offx;
            const float y0f = floorf(py), x0f = floorf(pxf);
            const float wy = py - y0f, wx = pxf - x0f;
            const int y0 = (int)y0f, x0 = (int)x0f;

            float a00 = (1.0f - wy) * (1.0f - wx);
            float a01 = (1.0f - wy) * wx;
            float a10 = wy * (1.0f - wx);
            float a11 = wy * wx;
            const bool vy0 = (y0 >= 0) && (y0 < HH);
            const bool vy1 = (y0 + 1 >= 0) && (y0 + 1 < HH);
            const bool vx0 = (x0 >= 0) && (x0 < WW);
            const bool vx1 = (x0 + 1 >= 0) && (x0 + 1 < WW);
            float4 w;
            w.x = (vy0 && vx0) ? a00 : 0.0f;
            w.y = (vy0 && vx1) ? a01 : 0.0f;
            w.z = (vy1 && vx0) ? a10 : 0.0f;
            w.w = (vy1 && vx1) ? a11 : 0.0f;

            const int y0c = min(max(y0, 0), HH - 1);
            const int y1c = min(max(y0 + 1, 0), HH - 1);
            const int x0c = min(max(x0, 0), WW - 1);
            const int x1c = min(max(x0 + 1, 0), WW - 1);
            const int dx1 = x1c - x0c;           // 0 or 1
            const int dyr = y1c - y0c;           // 0 or 1

            lymin = min(lymin, y0c); lymax = max(lymax, y1c);
            lxmin = min(lxmin, x0c); lxmax = max(lxmax, x1c);

            stateW[tap * 64 + p] = w;
            stateI[tap * 64 + p] =
                (unsigned int)(y0c * WW + x0c) | ((unsigned int)dx1 << 16) |
                ((unsigned int)dyr << 17);
        }
    }
    __syncthreads();
    atomicMin(&bnd[0], lymin); atomicMax(&bnd[1], lymax);
    atomicMin(&bnd[2], lxmin); atomicMax(&bnd[3], lxmax);
    __syncthreads();
    const int ymin = bnd[0], ymax = bnd[1], xmin = bnd[2], xmax = bnd[3];
    const bool fast = (ymax - ymin <= 9) && (xmax - xmin <= 75);

    const float* img = content + (size_t)b * CC * HWHW;

    f32x16 acc = {0, 0, 0, 0, 0, 0, 0, 0, 0, 0, 0, 0, 0, 0, 0, 0};

    const int lane = t & 63;
    const int hlf = lane >> 5;
    const int l31 = lane & 31;
    const int px_i = ((cg >> 1) * 32) + l31;   // A-frag pixel row
    const int n_i = ((cg & 1) * 32) + l31;     // B-frag out-channel col

    auto mfma_step = [&](int chunk) {
        const bf16x8* sampV = (const bf16x8*)sampU;
        const bf16x8* wV = (const bf16x8*)(WB2 + (size_t)chunk * 9216);
#pragma unroll
        for (int ks = 0; ks < 9; ++ks) {
            bf16x8 fa = sampV[(ks * 2 + hlf) * 64 + px_i];
            bf16x8 fb = wV[(ks * 2 + hlf) * 64 + n_i];
            acc = __builtin_amdgcn_mfma_f32_32x32x16_bf16(fa, fb, acc, 0, 0, 0);
        }
    };

    if (fast) {
        // ---- per-thread register caches (static-indexed, fully unrolled) ----
        unsigned int soff[24];   // staging: dword offset within a channel group
#pragma unroll
        for (int it = 0; it < 24; ++it) {
            const int i = it * 256 + t;
            const int ch = i / 760;              // 760 = 10*76
            const int rem = i - ch * 760;
            const int r = rem / 76;
            const int col = rem - r * 76;
            const int gy = min(ymin + r, HH - 1);    // ymin>=0
            const int gx = min(xmin + col, WW - 1);  // xmin>=0
            soff[it] = (unsigned int)((ch << 16) + (gy << 8) + gx);
        }
        float4 rW[9];
        unsigned int rA[9];      // taddr(10b) | dx<<20 | dyr<<21
#pragma unroll
        for (int tap = 0; tap < 9; ++tap) {
            rW[tap] = stateW[tap * 64 + px];
            const unsigned int ii = stateI[tap * 64 + px];
            const int ty = (int)((ii >> 8) & 255) - ymin;
            const int tx = (int)(ii & 255) - xmin;
            rA[tap] = (unsigned int)(ty * 76 + tx) |
                      (((ii >> 16) & 1u) << 20) | (((ii >> 17) & 1u) << 21);
        }

        const float* Tc = tileF + cg * 1520;   // this wave's 2-channel base (cg*2*760)

        auto stage = [&](const float* srcBase) {
#pragma unroll
            for (int it = 0; it < 24; ++it) {
                if (it < 23 || t < 192) {   // 6080 dwords total
                    __builtin_amdgcn_global_load_lds(
                        (gu32_t*)(srcBase + soff[it]),
                        (lu32_t*)(tileU + it * 256 + cg * 64), 4, 0, 0);
                }
            }
        };

        auto gather = [&](int hf) {
#pragma unroll 3
            for (int tap = 0; tap < 9; ++tap) {
                const float4 w = rW[tap];
                const unsigned int ra = rA[tap];
                const float* T0 = Tc + (ra & 1023u);
                const int dx = (int)((ra >> 20) & 1u);
                const float* T1 = (ra & (1u << 21)) ? (T0 + 76) : T0;
                const float s0 = w.x * T0[0] + w.y * T0[dx] + w.z * T1[0] + w.w * T1[dx];
                const float s1 = w.x * T0[760] + w.y * T0[760 + dx] +
                                 w.z * T1[760] + w.w * T1[760 + dx];
                const unsigned int pk = (unsigned int)f32_to_bf16(s0) |
                                        ((unsigned int)f32_to_bf16(s1) << 16);
                // k_local = tap*16 + hf*8 + cg*2 + {0,1}
                sampU[(tap * 2 + hf) * 256 + px * 4 + cg] = pk;
            }
        };

        stage(img);                           // chunk 0, half 0 (c0 = 0)
        __syncthreads();

        for (int chunk = 0; chunk < 4; ++chunk) {
            const int c0 = chunk * 16;
            gather(0);
            __syncthreads();                  // tile free, samp half0 ready
            stage(img + (size_t)(c0 + 8) * HWHW);
            __syncthreads();                  // tile ready (barrier drains vmcnt)
            gather(1);
            __syncthreads();                  // samp complete, tile free
            if (chunk < 3) stage(img + (size_t)(c0 + 16) * HWHW);  // overlaps MFMA
            mfma_step(chunk);
            __syncthreads();                  // samp reads done; stage drained
        }
    } else {
        // ---- fallback: global 4-corner gather (correct for any offsets) ----
        for (int chunk = 0; chunk < 4; ++chunk) {
            const int cbase = (chunk * 16 + cg * 4) << 16;   // HWHW == 1<<16
#pragma unroll 3
            for (int tap = 0; tap < 9; ++tap) {
                const float4 w = stateW[tap * 64 + px];
                const unsigned int ii = stateI[tap * 64 + px];
                const int i0 = (int)(ii & 0xFFFFu);
                const int dx = (int)((ii >> 16) & 1u);
                const int dyw = ((int)((ii >> 17) & 1u)) << 8;   // 0 or WW
                unsigned int pk0 = 0, pk1 = 0;
#pragma unroll
                for (int i = 0; i < 4; ++i) {
                    const int cb = cbase + (i << 16);
                    const float v00 = img[cb + i0];
                    const float v01 = img[cb + i0 + dx];
                    const float v10 = img[cb + i0 + dyw];
                    const float v11 = img[cb + i0 + dyw + dx];
                    const float s = w.x * v00 + w.y * v01 + w.z * v10 + w.w * v11;
                    const unsigned int u = f32_to_bf16(s);
                    if (i == 0) pk0 = u;
                    else if (i == 1) pk0 |= u << 16;
                    else if (i == 2) pk1 = u;
                    else pk1 |= u << 16;
                }
                uint2v v2 = {pk0, pk1};
                *(uint2v*)&sampU[(tap * 2 + (cg >> 1)) * 256 + px * 4 + (cg & 1) * 2] = v2;
            }
            __syncthreads();
            mfma_step(chunk);
            __syncthreads();
        }
    }

    // ---- epilogue: transpose via LDS (stride 65, bank-clean), coalesced out ----
    {
        const int n_l = (cg & 1) * 32 + l31;
        const int px_base = (cg >> 1) * 32 + 4 * hlf;
#pragma unroll
        for (int r = 0; r < 16; ++r) {
            const int row = px_base + (r & 3) + 8 * (r >> 2);
            ldsOut[n_l * 65 + row] = acc[r];
        }
    }
    __syncthreads();
    {
        float* base = out + (size_t)b * CC * HWHW + y * WW + xseg * 64;
        for (int i = t; i < 4096; i += 256) {
            const int n = i >> 6;
            const int p = i & 63;
            base[(size_t)n * HWHW + p] = ldsOut[n * 65 + p] + bias[n];
        }
    }
}

// ---------------------------------------------------------------------------
extern "C" void kernel_launch(void* const* d_in, const int* in_sizes, int n_in,
                              void* d_out, int out_size, void* d_ws, size_t ws_size,
                              hipStream_t stream) {
    const float* content  = (const float*)d_in[0];
    const float* blur     = (const float*)d_in[1];
    const float* offset_w = (const float*)d_in[2];
    const float* offset_b = (const float*)d_in[3];
    const float* dc_w     = (const float*)d_in[4];
    const float* dc_b     = (const float*)d_in[5];

    float* out0    = (float*)d_out;                                // (4,64,256,256)
    float* off_out = out0 + (size_t)BB * CC * HWHW;                // (4,18,256,256)

    float* wA = (float*)d_ws;                               // 10368 floats
    unsigned short* WB2 = (unsigned short*)(wA + CC * 9 * 18);  // 36864 bf16

    const int NPREP = CC * 9 * 18 + 4 * 18 * 64 * 8;        // 47232
    prep_weights<<<(NPREP + 255) / 256, 256, 0, stream>>>(offset_w, dc_w, wA, WB2);
    offset_conv<<<BB * HH, 256, 0, stream>>>(blur, wA, offset_b, off_out);
    deform_mfma<<<BB * HH * 4, 256, 0, stream>>>(content, off_out, WB2, dc_b, out0);
}

// Round 3
// 433.489 us; speedup vs baseline: 1.4290x; 1.2838x over previous
//
#include <hip/hip_runtime.h>

// Problem constants: B=4, C=64 (in & out for deform), H=W=256.
#define BB 4
#define CC 64
#define HH 256
#define WW 256
#define HWHW 65536

typedef __bf16 bf16x8 __attribute__((ext_vector_type(8)));
typedef float f32x16 __attribute__((ext_vector_type(16)));
typedef unsigned int uint2v __attribute__((ext_vector_type(2)));

__device__ __forceinline__ unsigned short f32_to_bf16(float s) {
    unsigned int xi = __builtin_bit_cast(unsigned int, s);
    unsigned int r = (xi + 0x7fffu + ((xi >> 16) & 1u)) >> 16;  // RNE
    return (unsigned short)r;
}

// ---------------------------------------------------------------------------
// Prep:
//   wA[c][k][o18]  fp32, from offset_w[o][c][ky][kx]  (offset conv weights)
//   WB2: bf16 deform weights, TAP-MAJOR K order:
//        [chunk(4)][kslot(18)][n(64)][j(8)], k_local = kslot*8+j,
//        tap = k_local/16, c = chunk*16 + (k_local%16), value = dc_w[n][c][tap]
// ---------------------------------------------------------------------------
__global__ void prep_weights(const float* __restrict__ offset_w,
                             const float* __restrict__ dc_w,
                             float* __restrict__ wA,
                             unsigned short* __restrict__ WB2) {
    int idx = blockIdx.x * 256 + threadIdx.x;
    const int NA = CC * 9 * 18;            // 10368
    const int NB = 4 * 18 * 64 * 8;        // 36864
    if (idx < NA) {
        int c = idx / (9 * 18);
        int k = (idx / 18) % 9;
        int o = idx % 18;
        wA[idx] = offset_w[(o * CC + c) * 9 + k];
    }
    int j = idx - NA;
    if (j >= 0 && j < NB) {
        int chunk = j / 9216;              // 9216 = 18*64*8
        int rem = j - chunk * 9216;
        int kslot = rem >> 9;              // /(64*8)
        int n = (rem >> 3) & 63;
        int jj = rem & 7;
        int k_local = kslot * 8 + jj;      // < 144, tap-major
        int tap = k_local >> 4;
        int c_local = k_local & 15;
        int c = chunk * 16 + c_local;
        WB2[j] = f32_to_bf16(dc_w[(n * CC + c) * 9 + tap]);
    }
}

// ---------------------------------------------------------------------------
// Offset conv (unchanged, fp32-exact): 3x3, pad 1, 64 -> 18 channels.
// ---------------------------------------------------------------------------
__global__ __launch_bounds__(256) void offset_conv(
    const float* __restrict__ blur, const float* __restrict__ wA,
    const float* __restrict__ ob, float* __restrict__ offout) {
    const int x = threadIdx.x;
    const int y = blockIdx.x & (HH - 1);
    const int b = blockIdx.x >> 8;

    int rb[3], cx[3];
    float m[9];
#pragma unroll
    for (int dy = 0; dy < 3; ++dy) {
        int yy = y + dy - 1;
        rb[dy] = min(max(yy, 0), HH - 1) * WW;
        bool vy = (yy >= 0) && (yy < HH);
#pragma unroll
        for (int dx = 0; dx < 3; ++dx) {
            int xx = x + dx - 1;
            bool v = vy && (xx >= 0) && (xx < WW);
            m[dy * 3 + dx] = v ? 1.0f : 0.0f;
        }
    }
#pragma unroll
    for (int dx = 0; dx < 3; ++dx) cx[dx] = min(max(x + dx - 1, 0), WW - 1);

    float acc[18];
#pragma unroll
    for (int o = 0; o < 18; ++o) acc[o] = ob[o];

    const float* img = blur + (size_t)b * CC * HWHW;
    for (int c = 0; c < CC; ++c) {
        const float* pl = img + c * HWHW;
        float s[9];
#pragma unroll
        for (int dy = 0; dy < 3; ++dy)
#pragma unroll
            for (int dx = 0; dx < 3; ++dx)
                s[dy * 3 + dx] = pl[rb[dy] + cx[dx]] * m[dy * 3 + dx];

        const float* wp = wA + c * 9 * 18;
#pragma unroll
        for (int k = 0; k < 9; ++k) {
            float sv = s[k];
#pragma unroll
            for (int o = 0; o < 18; ++o)
                acc[o] = fmaf(sv, wp[k * 18 + o], acc[o]);
        }
    }

    float* op = offout + ((size_t)b * 18) * HWHW + y * WW + x;
#pragma unroll
    for (int o = 0; o < 18; ++o) op[(size_t)o * HWHW] = acc[o];
}

// ---------------------------------------------------------------------------
// NCHW -> NHWC transpose of content into workspace: ct[(b*HW + p)*64 + c].
// ---------------------------------------------------------------------------
__global__ __launch_bounds__(256) void nchw_to_nhwc(
    const float* __restrict__ in, float* __restrict__ ct) {
    __shared__ float tile[64][65];
    const int t = threadIdx.x;
    const int blk = blockIdx.x;
    const int xseg = blk & 3;
    const int y = (blk >> 2) & (HH - 1);
    const int b = blk >> 10;
    const int px = t & 63;
    const int q = t >> 6;

    const float* src = in + (size_t)b * CC * HWHW + y * WW + xseg * 64;
#pragma unroll
    for (int i = 0; i < 16; ++i) {
        const int c = i * 4 + q;
        tile[c][px] = src[(size_t)c * HWHW + px];
    }
    __syncthreads();
    float* dst = ct + ((size_t)b * HWHW + y * WW + xseg * 64) * 64;
#pragma unroll
    for (int i = 0; i < 16; ++i) {
        const int p = i * 4 + q;
        dst[(size_t)p * 64 + px] = tile[px][p];   // lane = channel, coalesced
    }
}

// ---------------------------------------------------------------------------
// Deformable conv as implicit GEMM on MFMA — NHWC coalesced producer.
// LDS: samp 18432 + stateW 9216 + stateV 9216 = 36864 -> 4 blocks/CU.
// ---------------------------------------------------------------------------
__global__ __launch_bounds__(256, 4) void deform_mfma_nhwc(
    const float* __restrict__ ct, const float* __restrict__ offs,
    const unsigned short* __restrict__ WB2, const float* __restrict__ bias,
    float* __restrict__ out) {
    __shared__ __align__(16) char ldsbuf[36864];
    unsigned int* sampU = (unsigned int*)ldsbuf;            // [18][64][4] u32
    float4* stateW = (float4*)(ldsbuf + 18432);             // [576]
    uint4* stateV = (uint4*)(ldsbuf + 27648);               // [576]
    float* ldsOut = (float*)ldsbuf;                         // [64][65] epilogue alias

    const int t = threadIdx.x;
    const int blk = blockIdx.x;
    const int xseg = blk & 3;
    const int y = (blk >> 2) & (HH - 1);
    const int b = blk >> 10;

    // ---- phase 0: bilinear state for 64 px x 9 taps ----
    {
        const float* offbase = offs + (size_t)b * 18 * HWHW + y * WW + xseg * 64;
        for (int i = t; i < 576; i += 256) {
            const int p = i & 63;
            const int tap = i >> 6;
            const int ky = tap / 3, kx = tap - ky * 3;
            const float offy = offbase[(size_t)(2 * tap) * HWHW + p];
            const float offx = offbase[(size_t)(2 * tap + 1) * HWHW + p];
            const float py = (float)(y + ky - 1) + offy;
            const float pxf = (float)(xseg * 64 + p + kx - 1) + offx;
            const float y0f = floorf(py), x0f = floorf(pxf);
            const float wy = py - y0f, wx = pxf - x0f;
            const int y0 = (int)y0f, x0 = (int)x0f;

            float a00 = (1.0f - wy) * (1.0f - wx);
            float a01 = (1.0f - wy) * wx;
            float a10 = wy * (1.0f - wx);
            float a11 = wy * wx;
            const bool vy0 = (y0 >= 0) && (y0 < HH);
            const bool vy1 = (y0 + 1 >= 0) && (y0 + 1 < HH);
            const bool vx0 = (x0 >= 0) && (x0 < WW);
            const bool vx1 = (x0 + 1 >= 0) && (x0 + 1 < WW);
            float4 w;
            w.x = (vy0 && vx0) ? a00 : 0.0f;
            w.y = (vy0 && vx1) ? a01 : 0.0f;
            w.z = (vy1 && vx0) ? a10 : 0.0f;
            w.w = (vy1 && vx1) ? a11 : 0.0f;

            const int y0c = min(max(y0, 0), HH - 1);
            const int y1c = min(max(y0 + 1, 0), HH - 1);
            const int x0c = min(max(x0, 0), WW - 1);
            const int x1c = min(max(x0 + 1, 0), WW - 1);
            const unsigned int v00 = (unsigned int)(y0c * WW + x0c) << 8;  // *256B
            const unsigned int dxb = (unsigned int)(x1c - x0c) << 8;       // 0|256
            const unsigned int dyb = (unsigned int)(y1c - y0c) << 16;      // 0|65536

            stateW[i] = w;
            uint4 v;
            v.x = v00;
            v.y = v00 + dxb;
            v.z = v00 + dyb;
            v.w = v00 + dyb + dxb;
            stateV[i] = v;
        }
    }
    __syncthreads();

    const char* ctb = (const char*)(ct + (size_t)b * HWHW * 64);

    f32x16 acc = {0, 0, 0, 0, 0, 0, 0, 0, 0, 0, 0, 0, 0, 0, 0, 0};

    const int lane = t & 63;
    const int wv = t >> 6;
    const int l3 = lane >> 3;            // pair sub-index 0..7
    const int clb = (lane & 7) * 8;      // lane's 2-channel byte offset
    const int hlf = lane >> 5;
    const int l31 = lane & 31;
    const int px_i = ((wv >> 1) * 32) + l31;   // A-frag pixel row
    const int n_i = ((wv & 1) * 32) + l31;     // B-frag out-channel col

    for (int chunk = 0; chunk < 4; ++chunk) {
        // ---- producer: 144 pairs/wave, 8 pairs/iter, 2 channels/lane ----
        {
            const int cb = chunk * 64 + clb;   // chunk's 16-channel byte window
#pragma unroll 6
            for (int it = 0; it < 18; ++it) {
                const int j = wv * 144 + it * 8 + l3;
                const float4 w = stateW[j];
                const uint4 vo = stateV[j];
                const float2 v00 = *(const float2*)(ctb + (vo.x + cb));
                const float2 v01 = *(const float2*)(ctb + (vo.y + cb));
                const float2 v10 = *(const float2*)(ctb + (vo.z + cb));
                const float2 v11 = *(const float2*)(ctb + (vo.w + cb));
                const float s0 = w.x * v00.x + w.y * v01.x + w.z * v10.x + w.w * v11.x;
                const float s1 = w.x * v00.y + w.y * v01.y + w.z * v10.y + w.w * v11.y;
                unsigned int pk;
                asm("v_cvt_pk_bf16_f32 %0, %1, %2" : "=v"(pk) : "v"(s0), "v"(s1));
                const int tap = j >> 6;
                const int px = j & 63;
                sampU[(tap * 2 + ((lane >> 2) & 1)) * 256 + px * 4 + (lane & 3)] = pk;
            }
        }
        __syncthreads();

        // ---- MFMA: 9 x K16; B-frags direct from global (L2-hot 36KB) ----
        {
            const bf16x8* sampV = (const bf16x8*)sampU;
            const bf16x8* wV = (const bf16x8*)(WB2 + (size_t)chunk * 9216);
#pragma unroll
            for (int ks = 0; ks < 9; ++ks) {
                bf16x8 fa = sampV[(ks * 2 + hlf) * 64 + px_i];
                bf16x8 fb = wV[(ks * 2 + hlf) * 64 + n_i];
                acc = __builtin_amdgcn_mfma_f32_32x32x16_bf16(fa, fb, acc, 0, 0, 0);
            }
        }
        __syncthreads();
    }

    // ---- epilogue: transpose via LDS (stride 65, bank-clean), coalesced out ----
    {
        const int n_l = (wv & 1) * 32 + l31;
        const int px_base = (wv >> 1) * 32 + 4 * hlf;
#pragma unroll
        for (int r = 0; r < 16; ++r) {
            const int row = px_base + (r & 3) + 8 * (r >> 2);
            ldsOut[n_l * 65 + row] = acc[r];
        }
    }
    __syncthreads();
    {
        float* base = out + (size_t)b * CC * HWHW + y * WW + xseg * 64;
        for (int i = t; i < 4096; i += 256) {
            const int n = i >> 6;
            const int p = i & 63;
            base[(size_t)n * HWHW + p] = ldsOut[n * 65 + p] + bias[n];
        }
    }
}

// ---------------------------------------------------------------------------
// Fallback deform (only if workspace too small): global scattered gather,
// tap-major K (matches WB2).
// ---------------------------------------------------------------------------
__global__ __launch_bounds__(256) void deform_mfma_gather(
    const float* __restrict__ content, const float* __restrict__ offs,
    const unsigned short* __restrict__ WB2, const float* __restrict__ bias,
    float* __restrict__ out) {
    __shared__ __align__(16) char ldsbuf[29952];
    unsigned int* sampU = (unsigned int*)ldsbuf;            // [18][64][4]
    float4* stateW = (float4*)(ldsbuf + 18432);             // [576]
    unsigned int* stateI = (unsigned int*)(ldsbuf + 27648); // [576]
    float* ldsOut = (float*)ldsbuf;

    const int t = threadIdx.x;
    const int px = t & 63;
    const int cg = t >> 6;
    const int blk = blockIdx.x;
    const int xseg = blk & 3;
    const int y = (blk >> 2) & (HH - 1);
    const int b = blk >> 10;

    {
        const float* offbase = offs + (size_t)b * 18 * HWHW + y * WW + xseg * 64;
        for (int i = t; i < 576; i += 256) {
            const int p = i & 63;
            const int tap = i >> 6;
            const int ky = tap / 3, kx = tap - ky * 3;
            const float offy = offbase[(size_t)(2 * tap) * HWHW + p];
            const float offx = offbase[(size_t)(2 * tap + 1) * HWHW + p];
            const float py = (float)(y + ky - 1) + offy;
            const float pxf = (float)(xseg * 64 + p + kx - 1) + offx;
            const float y0f = floorf(py), x0f = floorf(pxf);
            const float wy = py - y0f, wx = pxf - x0f;
            const int y0 = (int)y0f, x0 = (int)x0f;
            float a00 = (1.0f - wy) * (1.0f - wx);
            float a01 = (1.0f - wy) * wx;
            float a10 = wy * (1.0f - wx);
            float a11 = wy * wx;
            const bool vy0 = (y0 >= 0) && (y0 < HH);
            const bool vy1 = (y0 + 1 >= 0) && (y0 + 1 < HH);
            const bool vx0 = (x0 >= 0) && (x0 < WW);
            const bool vx1 = (x0 + 1 >= 0) && (x0 + 1 < WW);
            float4 w;
            w.x = (vy0 && vx0) ? a00 : 0.0f;
            w.y = (vy0 && vx1) ? a01 : 0.0f;
            w.z = (vy1 && vx0) ? a10 : 0.0f;
            w.w = (vy1 && vx1) ? a11 : 0.0f;
            const int y0c = min(max(y0, 0), HH - 1);
            const int y1c = min(max(y0 + 1, 0), HH - 1);
            const int x0c = min(max(x0, 0), WW - 1);
            const int x1c = min(max(x0 + 1, 0), WW - 1);
            stateW[i] = w;
            stateI[i] = (unsigned int)(y0c * WW + x0c) |
                        ((unsigned int)(x1c - x0c) << 16) |
                        ((unsigned int)(y1c - y0c) << 17);
        }
    }
    __syncthreads();

    const float* img = content + (size_t)b * CC * HWHW;
    f32x16 acc = {0, 0, 0, 0, 0, 0, 0, 0, 0, 0, 0, 0, 0, 0, 0, 0};
    const int lane = t & 63;
    const int hlf = lane >> 5;
    const int l31 = lane & 31;
    const int px_i = ((cg >> 1) * 32) + l31;
    const int n_i = ((cg & 1) * 32) + l31;

    for (int chunk = 0; chunk < 4; ++chunk) {
        const int cbase = (chunk * 16 + cg * 4) << 16;
#pragma unroll 3
        for (int tap = 0; tap < 9; ++tap) {
            const float4 w = stateW[tap * 64 + px];
            const unsigned int ii = stateI[tap * 64 + px];
            const int i0 = (int)(ii & 0xFFFFu);
            const int dx = (int)((ii >> 16) & 1u);
            const int dyw = ((int)((ii >> 17) & 1u)) << 8;
            unsigned int pk0 = 0, pk1 = 0;
#pragma unroll
            for (int i = 0; i < 4; ++i) {
                const int cb = cbase + (i << 16);
                const float v00 = img[cb + i0];
                const float v01 = img[cb + i0 + dx];
                const float v10 = img[cb + i0 + dyw];
                const float v11 = img[cb + i0 + dyw + dx];
                const float s = w.x * v00 + w.y * v01 + w.z * v10 + w.w * v11;
                const unsigned int u = f32_to_bf16(s);
                if (i == 0) pk0 = u;
                else if (i == 1) pk0 |= u << 16;
                else if (i == 2) pk1 = u;
                else pk1 |= u << 16;
            }
            uint2v v2 = {pk0, pk1};
            *(uint2v*)&sampU[(tap * 2 + (cg >> 1)) * 256 + px * 4 + (cg & 1) * 2] = v2;
        }
        __syncthreads();
        {
            const bf16x8* sampV = (const bf16x8*)sampU;
            const bf16x8* wV = (const bf16x8*)(WB2 + (size_t)chunk * 9216);
#pragma unroll
            for (int ks = 0; ks < 9; ++ks) {
                bf16x8 fa = sampV[(ks * 2 + hlf) * 64 + px_i];
                bf16x8 fb = wV[(ks * 2 + hlf) * 64 + n_i];
                acc = __builtin_amdgcn_mfma_f32_32x32x16_bf16(fa, fb, acc, 0, 0, 0);
            }
        }
        __syncthreads();
    }

    {
        const int n_l = (cg & 1) * 32 + l31;
        const int px_base = (cg >> 1) * 32 + 4 * hlf;
#pragma unroll
        for (int r = 0; r < 16; ++r) {
            const int row = px_base + (r & 3) + 8 * (r >> 2);
            ldsOut[n_l * 65 + row] = acc[r];
        }
    }
    __syncthreads();
    {
        float* base = out + (size_t)b * CC * HWHW + y * WW + xseg * 64;
        for (int i = t; i < 4096; i += 256) {
            const int n = i >> 6;
            const int p = i & 63;
            base[(size_t)n * HWHW + p] = ldsOut[n * 65 + p] + bias[n];
        }
    }
}

// ---------------------------------------------------------------------------
extern "C" void kernel_launch(void* const* d_in, const int* in_sizes, int n_in,
                              void* d_out, int out_size, void* d_ws, size_t ws_size,
                              hipStream_t stream) {
    const float* content  = (const float*)d_in[0];
    const float* blur     = (const float*)d_in[1];
    const float* offset_w = (const float*)d_in[2];
    const float* offset_b = (const float*)d_in[3];
    const float* dc_w     = (const float*)d_in[4];
    const float* dc_b     = (const float*)d_in[5];

    float* out0    = (float*)d_out;                                // (4,64,256,256)
    float* off_out = out0 + (size_t)BB * CC * HWHW;                // (4,18,256,256)

    float* wA = (float*)d_ws;                                   // 10368 floats
    unsigned short* WB2 = (unsigned short*)(wA + CC * 9 * 18);  // 36864 bf16

    const size_t CT_OFF = 131072;                               // bytes
    const size_t WS_NEED = CT_OFF + (size_t)BB * HWHW * CC * 4; // + 64 MiB

    const int NPREP = CC * 9 * 18 + 4 * 18 * 64 * 8;        // 47232
    prep_weights<<<(NPREP + 255) / 256, 256, 0, stream>>>(offset_w, dc_w, wA, WB2);
    offset_conv<<<BB * HH, 256, 0, stream>>>(blur, wA, offset_b, off_out);

    if (ws_size >= WS_NEED) {
        float* ct = (float*)((char*)d_ws + CT_OFF);
        nchw_to_nhwc<<<BB * HH * 4, 256, 0, stream>>>(content, ct);
        deform_mfma_nhwc<<<BB * HH * 4, 256, 0, stream>>>(ct, off_out, WB2, dc_b, out0);
    } else {
        deform_mfma_gather<<<BB * HH * 4, 256, 0, stream>>>(content, off_out, WB2, dc_b, out0);
    }
}